// Round 1
// baseline (74.503 us; speedup 1.0000x reference)
//
#include <hip/hip_runtime.h>

constexpr int   NPTS     = 8192;
constexpr float MIN_DIST = 1.0f;   // RADIUS * 2 * scale = 0.5 * 2 * 1.0

// One block per row i. Computes:
//   row_dist[i] = sum_j dist(i,j)
//   row_int[i]  = sum_j relu(MIN_DIST - dist(i,j))  minus the masked prefix
//                 run j in [i, k_i) where k_i = first j>i with dist>MIN_DIST.
__global__ __launch_bounds__(256)
void row_kernel(const float* __restrict__ x, const float* __restrict__ y,
                const float* __restrict__ z, float* __restrict__ row_dist,
                float* __restrict__ row_int) {
    const int i   = blockIdx.x;
    const int tid = threadIdx.x;
    const float xi = x[i], yi = y[i], zi = z[i];

    float sd = 0.f, sr = 0.f;
    int kmin = NPTS;
    for (int j = tid; j < NPTS; j += 256) {
        float dx = x[j] - xi, dy = y[j] - yi, dz = z[j] - zi;
        float d  = sqrtf(dx * dx + dy * dy + dz * dz);
        sd += d;
        sr += fmaxf(MIN_DIST - d, 0.f);
        if (j > i && d > MIN_DIST && j < kmin) kmin = j;
    }

    __shared__ float s1[256];
    __shared__ float s2[256];
    __shared__ int   s3[256];
    s1[tid] = sd; s2[tid] = sr; s3[tid] = kmin;
    __syncthreads();
    for (int s = 128; s > 0; s >>= 1) {
        if (tid < s) {
            s1[tid] += s1[tid + s];
            s2[tid] += s2[tid + s];
            s3[tid]  = min(s3[tid], s3[tid + s]);
        }
        __syncthreads();
    }
    const float rowd = s1[0];
    const float rowr = s2[0];
    const int   k    = s3[0];
    __syncthreads();

    // Subtract the masked contiguous run [i, k): all have dist <= MIN_DIST.
    float sm = 0.f;
    for (int j = i + tid; j < k; j += 256) {
        float dx = x[j] - xi, dy = y[j] - yi, dz = z[j] - zi;
        float d  = sqrtf(dx * dx + dy * dy + dz * dz);
        sm += fmaxf(MIN_DIST - d, 0.f);
    }
    s1[tid] = sm;
    __syncthreads();
    for (int s = 128; s > 0; s >>= 1) {
        if (tid < s) s1[tid] += s1[tid + s];
        __syncthreads();
    }
    if (tid == 0) {
        row_dist[i] = rowd;
        row_int[i]  = rowr - s1[0];
    }
}

// Single block: deterministic final reduce + the O(N) loss terms.
__global__ __launch_bounds__(256)
void finalize_kernel(const float* __restrict__ y, const float* __restrict__ z,
                     const float* __restrict__ row_dist,
                     const float* __restrict__ row_int,
                     float* __restrict__ out) {
    const int tid = threadIdx.x;
    float sd = 0.f, si = 0.f, sfix = 0.f, snoise = 0.f;
    for (int i = tid; i < NPTS; i += 256) {
        sd += row_dist[i];
        si += row_int[i];
        const float yv = y[i], zv = z[i];
        sfix += fmaxf(yv - 1.f, 0.f) + fmaxf(-1.f - yv, 0.f);
        sfix += fmaxf(zv - 1.f, 0.f) + fmaxf(-1.f - zv, 0.f);
        if (i < NPTS - 2) {
            const float d2y = y[i + 2] - 2.f * y[i + 1] + y[i];
            const float d2z = z[i + 2] - 2.f * z[i + 1] + z[i];
            snoise += d2y * d2y + d2z * d2z;
        }
    }
    __shared__ float a[256], b[256], c[256], d[256];
    a[tid] = sd; b[tid] = si; c[tid] = sfix; d[tid] = snoise;
    __syncthreads();
    for (int s = 128; s > 0; s >>= 1) {
        if (tid < s) {
            a[tid] += a[tid + s];
            b[tid] += b[tid + s];
            c[tid] += c[tid + s];
            d[tid] += d[tid + s];
        }
        __syncthreads();
    }
    if (tid == 0)
        out[0] = c[0] + a[0] / 10000.f + b[0] + 10.f * d[0];
}

extern "C" void kernel_launch(void* const* d_in, const int* in_sizes, int n_in,
                              void* d_out, int out_size, void* d_ws, size_t ws_size,
                              hipStream_t stream) {
    const float* x = (const float*)d_in[0];
    const float* y = (const float*)d_in[1];
    const float* z = (const float*)d_in[2];
    float* out      = (float*)d_out;
    float* row_dist = (float*)d_ws;
    float* row_int  = row_dist + NPTS;

    row_kernel<<<NPTS, 256, 0, stream>>>(x, y, z, row_dist, row_int);
    finalize_kernel<<<1, 256, 0, stream>>>(y, z, row_dist, row_int, out);
}

// Round 2
// 42.887 us; speedup vs baseline: 1.7372x; 1.7372x over previous
//
#include <hip/hip_runtime.h>

constexpr int N = 8192;
// MIN_DIST = RADIUS*2*scale = 1.0f

__device__ __forceinline__ float fsqrt(float v) { return __builtin_amdgcn_sqrtf(v); }

// Each block owns 16 rows: 8 from the top of the triangle (topBase..topBase+7)
// and 8 mirrored from the bottom (botBase..botBase+7), so per-block work is
// constant (~N columns total) while only scanning j >= row (upper triangle).
// Outputs per-row upper sums: row_sd[i] = sum_{j>=i} d(i,j),
//                             row_sr[i] = sum_{j>=i} relu(1-d)   (diag => +1)
__global__ __launch_bounds__(256)
void pair_kernel(const float* __restrict__ x, const float* __restrict__ y,
                 const float* __restrict__ z,
                 float* __restrict__ row_sd, float* __restrict__ row_sr) {
    const int b       = blockIdx.x;       // 0..511
    const int tid     = threadIdx.x;
    const int topBase = 8 * b;            // rows 0..4095
    const int botBase = N - 8 * (b + 1);  // rows 8191..4096

    float xr[16], yr[16], zr[16];
#pragma unroll
    for (int r = 0; r < 8; ++r) {
        xr[r]     = x[topBase + r]; yr[r]     = y[topBase + r]; zr[r]     = z[topBase + r];
        xr[8 + r] = x[botBase + r]; yr[8 + r] = y[botBase + r]; zr[8 + r] = z[botBase + r];
    }
    float sd[16], sr[16];
#pragma unroll
    for (int r = 0; r < 16; ++r) { sd[r] = 0.f; sr[r] = 0.f; }

#pragma unroll
    for (int g = 0; g < 2; ++g) {
        const int base = g ? botBase : topBase;
        const int ro   = g * 8;

        // head chunk [base, base+256): per-row mask j >= i
        {
            const int j = base + tid;
            if (j < N) {
                const float xj = x[j], yj = y[j], zj = z[j];
#pragma unroll
                for (int r = 0; r < 8; ++r) {
                    const float dx = xj - xr[ro + r];
                    const float dy = yj - yr[ro + r];
                    const float dz = zj - zr[ro + r];
                    const float d  = fsqrt(dx * dx + dy * dy + dz * dz);
                    if (tid >= r) {                 // j >= base + r
                        sd[ro + r] += d;
                        sr[ro + r] += fmaxf(1.f - d, 0.f);
                    }
                }
            }
        }
        // clean tail: all j > every row index in this group
        for (int j = base + 256 + tid; j < N; j += 256) {
            const float xj = x[j], yj = y[j], zj = z[j];
#pragma unroll
            for (int r = 0; r < 8; ++r) {
                const float dx = xj - xr[ro + r];
                const float dy = yj - yr[ro + r];
                const float dz = zj - zr[ro + r];
                const float d  = fsqrt(dx * dx + dy * dy + dz * dz);
                sd[ro + r] += d;
                sr[ro + r] += fmaxf(1.f - d, 0.f);
            }
        }
    }

    // reduce each row across 256 threads: wave shuffle, then LDS across 4 waves
    const int lane = tid & 63, wave = tid >> 6;
    __shared__ float lds_sd[4][16];
    __shared__ float lds_sr[4][16];
#pragma unroll
    for (int r = 0; r < 16; ++r) {
        float a = sd[r], c = sr[r];
#pragma unroll
        for (int off = 32; off; off >>= 1) {
            a += __shfl_down(a, off);
            c += __shfl_down(c, off);
        }
        if (lane == 0) { lds_sd[wave][r] = a; lds_sr[wave][r] = c; }
    }
    __syncthreads();
    if (tid < 16) {
        const float a = lds_sd[0][tid] + lds_sd[1][tid] + lds_sd[2][tid] + lds_sd[3][tid];
        const float c = lds_sr[0][tid] + lds_sr[1][tid] + lds_sr[2][tid] + lds_sr[3][tid];
        const int  i  = (tid < 8) ? (topBase + tid) : (botBase + tid - 8);
        row_sd[i] = a;
        row_sr[i] = c;
    }
}

// One wave per row: scan from the diagonal in 64-wide chunks; the masked run
// is [i, k) where k = first j with d > 1. Accumulate sum of relu(1-d)=1-d over
// the run. OOB lanes get d=2 (>1) so row-end terminates the run correctly.
__global__ __launch_bounds__(256)
void corr_kernel(const float* __restrict__ x, const float* __restrict__ y,
                 const float* __restrict__ z, float* __restrict__ row_corr) {
    const int lane = threadIdx.x & 63;
    const int i    = blockIdx.x * 4 + (threadIdx.x >> 6);
    const float xi = x[i], yi = y[i], zi = z[i];
    float corr = 0.f;
    for (int base = i; base < N; base += 64) {
        const int j = base + lane;
        float d = 2.f;
        if (j < N) {
            const float dx = x[j] - xi, dy = y[j] - yi, dz = z[j] - zi;
            d = fsqrt(dx * dx + dy * dy + dz * dz);
        }
        const unsigned long long far = __ballot(d > 1.0f);
        const int stop = far ? __builtin_ctzll(far) : 64;
        if (lane < stop) corr += 1.f - d;
        if (far) break;
    }
#pragma unroll
    for (int off = 32; off; off >>= 1) corr += __shfl_down(corr, off);
    if (lane == 0) row_corr[i] = corr;
}

// Single block, deterministic: totals + O(N) terms.
//   sum_dist  = 2*A            (A = sum row_sd, diagonal is 0)
//   sum_relu  = 2*B - N        (B = sum row_sr; diag counted once per row in B)
//   intersect = sum_relu - C   (C = sum row_corr, masked prefix runs)
__global__ __launch_bounds__(256)
void finalize_kernel(const float* __restrict__ y, const float* __restrict__ z,
                     const float* __restrict__ row_sd, const float* __restrict__ row_sr,
                     const float* __restrict__ row_corr, float* __restrict__ out) {
    const int tid = threadIdx.x;
    float A = 0.f, B = 0.f, C = 0.f, sfix = 0.f, snoise = 0.f;
    for (int i = tid; i < N; i += 256) {
        A += row_sd[i];
        B += row_sr[i];
        C += row_corr[i];
        const float yv = y[i], zv = z[i];
        sfix += fmaxf(yv - 1.f, 0.f) + fmaxf(-1.f - yv, 0.f)
              + fmaxf(zv - 1.f, 0.f) + fmaxf(-1.f - zv, 0.f);
        if (i < N - 2) {
            const float d2y = y[i + 2] - 2.f * y[i + 1] + y[i];
            const float d2z = z[i + 2] - 2.f * z[i + 1] + z[i];
            snoise += d2y * d2y + d2z * d2z;
        }
    }
    __shared__ float s[5][256];
    s[0][tid] = A; s[1][tid] = B; s[2][tid] = C; s[3][tid] = sfix; s[4][tid] = snoise;
    __syncthreads();
    for (int st = 128; st; st >>= 1) {
        if (tid < st) {
#pragma unroll
            for (int k = 0; k < 5; ++k) s[k][tid] += s[k][tid + st];
        }
        __syncthreads();
    }
    if (tid == 0)
        out[0] = s[3][0] + (2.f * s[0][0]) / 10000.f
               + (2.f * s[1][0] - (float)N - s[2][0]) + 10.f * s[4][0];
}

extern "C" void kernel_launch(void* const* d_in, const int* in_sizes, int n_in,
                              void* d_out, int out_size, void* d_ws, size_t ws_size,
                              hipStream_t stream) {
    const float* x = (const float*)d_in[0];
    const float* y = (const float*)d_in[1];
    const float* z = (const float*)d_in[2];
    float* out      = (float*)d_out;
    float* row_sd   = (float*)d_ws;
    float* row_sr   = row_sd + N;
    float* row_corr = row_sr + N;

    pair_kernel<<<N / 16, 256, 0, stream>>>(x, y, z, row_sd, row_sr);
    corr_kernel<<<N / 4, 256, 0, stream>>>(x, y, z, row_corr);
    finalize_kernel<<<1, 256, 0, stream>>>(y, z, row_sd, row_sr, row_corr, out);
}

// Round 3
// 35.322 us; speedup vs baseline: 2.1093x; 1.2142x over previous
//
#include <hip/hip_runtime.h>

constexpr int N = 8192;
// MIN_DIST = RADIUS*2*scale = 1.0f
// T = sum_{i=0}^{N-1} (N-i) = N(N+1)/2, exact in f32
constexpr float TRI = 33558528.0f;

__device__ __forceinline__ float fsqrt(float v) { return __builtin_amdgcn_sqrtf(v); }

// Fused kernel.
//  blocks [0,1024):   pair tiles — rows {4b..4b+3} (top) + {N-4b-4..N-4b-1} (bot),
//                     upper-triangle scan j >= i. Writes per-row:
//                       row_sd[i] = sum_{j>=i} d(i,j)
//                       row_sm[i] = sum_{j>=i} min(d,1)   (relu sum = (N-i) - row_sm)
//  blocks [1024,2048): masked-prefix-run scan, 2 rows per wave:
//                       row_corr[i] = sum over run [i,k) of (1-d), k = first d>1.
__global__ __launch_bounds__(256, 4)
void main_kernel(const float* __restrict__ x, const float* __restrict__ y,
                 const float* __restrict__ z,
                 float* __restrict__ row_sd, float* __restrict__ row_sm,
                 float* __restrict__ row_corr) {
    const int tid  = threadIdx.x;
    const int lane = tid & 63;
    const int wave = tid >> 6;
    __shared__ float lsd[4][8];
    __shared__ float lsm[4][8];

    if (blockIdx.x < 1024) {
        const int b       = blockIdx.x;
        const int topBase = 4 * b;            // 0..4092
        const int botBase = N - 4 * (b + 1);  // 8188..4096

        float xr[8], yr[8], zr[8];
#pragma unroll
        for (int r = 0; r < 4; ++r) {
            xr[r]     = x[topBase + r]; yr[r]     = y[topBase + r]; zr[r]     = z[topBase + r];
            xr[4 + r] = x[botBase + r]; yr[4 + r] = y[botBase + r]; zr[4 + r] = z[botBase + r];
        }
        float sd[8], sm[8];
#pragma unroll
        for (int r = 0; r < 8; ++r) { sd[r] = 0.f; sm[r] = 0.f; }

#pragma unroll
        for (int g = 0; g < 2; ++g) {
            const int base = g ? botBase : topBase;
            const int ro   = g * 4;

            // diagonal chunk [base, base+256): predicated (j >= i, j < N)
            {
                const int   j  = base + tid;
                const int   jc = (j < N) ? j : (N - 1);
                const float cx = x[jc], cy = y[jc], cz = z[jc];
#pragma unroll
                for (int r = 0; r < 4; ++r) {
                    const float dx = cx - xr[ro + r], dy = cy - yr[ro + r], dz = cz - zr[ro + r];
                    const float d  = fsqrt(dx * dx + dy * dy + dz * dz);
                    if (tid >= r && j < N) { sd[ro + r] += d; sm[ro + r] += fminf(d, 1.f); }
                }
            }
            // full middle chunks, software-pipelined loads
            int j0 = base + 256;
            if (j0 + 256 <= N) {
                float nx = x[j0 + tid], ny = y[j0 + tid], nz = z[j0 + tid];
                while (true) {
                    const float cx = nx, cy = ny, cz = nz;
                    const bool  more = (j0 + 512 <= N);
                    if (more) {
                        const int jn = j0 + 256 + tid;
                        nx = x[jn]; ny = y[jn]; nz = z[jn];
                    }
#pragma unroll
                    for (int r = 0; r < 4; ++r) {
                        const float dx = cx - xr[ro + r], dy = cy - yr[ro + r], dz = cz - zr[ro + r];
                        const float d  = fsqrt(dx * dx + dy * dy + dz * dz);
                        sd[ro + r] += d; sm[ro + r] += fminf(d, 1.f);
                    }
                    j0 += 256;
                    if (!more) break;
                }
            }
            // tail partial chunk (j < N)
            if (j0 < N) {
                const int j = j0 + tid;
                if (j < N) {
                    const float cx = x[j], cy = y[j], cz = z[j];
#pragma unroll
                    for (int r = 0; r < 4; ++r) {
                        const float dx = cx - xr[ro + r], dy = cy - yr[ro + r], dz = cz - zr[ro + r];
                        const float d  = fsqrt(dx * dx + dy * dy + dz * dz);
                        sd[ro + r] += d; sm[ro + r] += fminf(d, 1.f);
                    }
                }
            }
        }

        // reduce 8 rows across 4 waves
#pragma unroll
        for (int r = 0; r < 8; ++r) {
            float a = sd[r], c = sm[r];
#pragma unroll
            for (int off = 32; off; off >>= 1) {
                a += __shfl_down(a, off);
                c += __shfl_down(c, off);
            }
            if (lane == 0) { lsd[wave][r] = a; lsm[wave][r] = c; }
        }
        __syncthreads();
        if (tid < 8) {
            const float a = lsd[0][tid] + lsd[1][tid] + lsd[2][tid] + lsd[3][tid];
            const float c = lsm[0][tid] + lsm[1][tid] + lsm[2][tid] + lsm[3][tid];
            const int   i = (tid < 4) ? (topBase + tid) : (botBase + tid - 4);
            row_sd[i] = a;
            row_sm[i] = c;
        }
    } else {
        // masked-prefix-run correction: 8 rows/block, 2 rows/wave
        const int cb = blockIdx.x - 1024;
#pragma unroll
        for (int rr = 0; rr < 2; ++rr) {
            const int   i  = 8 * cb + 2 * wave + rr;
            const float xi = x[i], yi = y[i], zi = z[i];
            float corr = 0.f;
            for (int jb = i; jb < N; jb += 64) {
                const int j = jb + lane;
                float d = 2.f;
                if (j < N) {
                    const float dx = x[j] - xi, dy = y[j] - yi, dz = z[j] - zi;
                    d = fsqrt(dx * dx + dy * dy + dz * dz);
                }
                const unsigned long long far = __ballot(d > 1.0f);
                const int stop = far ? __builtin_ctzll(far) : 64;
                if (lane < stop) corr += 1.f - d;
                if (far) break;
            }
#pragma unroll
            for (int off = 32; off; off >>= 1) corr += __shfl_down(corr, off);
            if (lane == 0) row_corr[i] = corr;
        }
    }
}

// Single block, deterministic:
//   A = sum row_sd, M = sum row_sm, C = sum row_corr
//   sum_dist  = 2A;  sum_relu = 2*(TRI - M) - N;  intersect = sum_relu - C
__global__ __launch_bounds__(256)
void finalize_kernel(const float* __restrict__ y, const float* __restrict__ z,
                     const float* __restrict__ row_sd, const float* __restrict__ row_sm,
                     const float* __restrict__ row_corr, float* __restrict__ out) {
    const int tid = threadIdx.x;
    float A = 0.f, M = 0.f, C = 0.f, sfix = 0.f, snoise = 0.f;
    for (int i = tid; i < N; i += 256) {
        A += row_sd[i];
        M += row_sm[i];
        C += row_corr[i];
        const float yv = y[i], zv = z[i];
        sfix += fmaxf(yv - 1.f, 0.f) + fmaxf(-1.f - yv, 0.f)
              + fmaxf(zv - 1.f, 0.f) + fmaxf(-1.f - zv, 0.f);
        if (i < N - 2) {
            const float d2y = y[i + 2] - 2.f * y[i + 1] + y[i];
            const float d2z = z[i + 2] - 2.f * z[i + 1] + z[i];
            snoise += d2y * d2y + d2z * d2z;
        }
    }
    __shared__ float s[5][256];
    s[0][tid] = A; s[1][tid] = M; s[2][tid] = C; s[3][tid] = sfix; s[4][tid] = snoise;
    __syncthreads();
    for (int st = 128; st; st >>= 1) {
        if (tid < st) {
#pragma unroll
            for (int k = 0; k < 5; ++k) s[k][tid] += s[k][tid + st];
        }
        __syncthreads();
    }
    if (tid == 0)
        out[0] = s[3][0] + (2.f * s[0][0]) / 10000.f
               + (2.f * (TRI - s[1][0]) - (float)N - s[2][0]) + 10.f * s[4][0];
}

extern "C" void kernel_launch(void* const* d_in, const int* in_sizes, int n_in,
                              void* d_out, int out_size, void* d_ws, size_t ws_size,
                              hipStream_t stream) {
    const float* x = (const float*)d_in[0];
    const float* y = (const float*)d_in[1];
    const float* z = (const float*)d_in[2];
    float* out      = (float*)d_out;
    float* row_sd   = (float*)d_ws;
    float* row_sm   = row_sd + N;
    float* row_corr = row_sm + N;

    main_kernel<<<2048, 256, 0, stream>>>(x, y, z, row_sd, row_sm, row_corr);
    finalize_kernel<<<1, 256, 0, stream>>>(y, z, row_sd, row_sm, row_corr, out);
}